// Round 7
// baseline (922.843 us; speedup 1.0000x reference)
//
#include <hip/hip_runtime.h>
#include <cstddef>
#include <cstdint>

#define BATCH 32
#define CCH   512
#define OCH   1024
#define HW    3136
#define WDIM  56
#define NKT   16           // 512 / BK, BK=32

typedef __attribute__((ext_vector_type(8))) short short8v;  // 8 bf16
typedef __attribute__((ext_vector_type(4))) float f32x4;

// pair of fp32 -> packed bf16 hi-word + lo-word (R1-proven numerics).
static __device__ __forceinline__ void cvt2(float x0, float x1,
                                            unsigned& hw, unsigned& lw) {
    unsigned u0 = __float_as_uint(x0), u1 = __float_as_uint(x1);
    hw = (u1 & 0xffff0000u) | (u0 >> 16);
    float l0 = x0 - __uint_as_float(u0 & 0xffff0000u);
    float l1 = x1 - __uint_as_float(u1 & 0xffff0000u);
    unsigned r0 = __float_as_uint(l0), r1 = __float_as_uint(l1);
    r0 = r0 + 0x7fffu + ((r0 >> 16) & 1u);
    r1 = r1 + 0x7fffu + ((r1 >> 16) & 1u);
    lw = (r1 & 0xffff0000u) | (r0 >> 16);
}

static __device__ __forceinline__ int physlot(int s, int row) {
    return (s ^ (row & 7) ^ ((row >> 3) & 7)) & 7;
}

static __device__ __forceinline__ short8v pack4(unsigned a, unsigned b,
                                                unsigned c, unsigned d) {
    union { uint4 u; short8v v; } x;
    x.u = make_uint4(a, b, c, d);
    return x.v;
}

// ---------------------------------------------------------------------------
// K0: pre-convert weights into fragment-image layout (R3-proven):
// wcvt[o][kt] = 128 B: phys slots 0-3 <- hi k-octets, 4-7 <- lo k-octets,
// pre-swizzled with physlot(s, o). GEMM reads fragments DIRECTLY from this.
// ---------------------------------------------------------------------------
__global__ __launch_bounds__(256) void preconv_w(
    const float* __restrict__ wp, unsigned char* __restrict__ wcvt)
{
    const int id = blockIdx.x * 256 + threadIdx.x;   // 16384 = 1024 o x 16 kt
    const int o = id >> 4, kt = id & 15;
    const float* p = wp + (size_t)o * CCH + kt * 32;
    unsigned char* dst = wcvt + (size_t)o * 2048 + kt * 128;
    float4 v[8];
#pragma unroll
    for (int r = 0; r < 8; ++r) v[r] = *(const float4*)(p + 4 * r);
#pragma unroll
    for (int oc = 0; oc < 4; ++oc) {
        unsigned h0, w0, h1, w1, h2, w2, h3, w3;
        cvt2(v[2*oc].x,   v[2*oc].y,   h0, w0);
        cvt2(v[2*oc].z,   v[2*oc].w,   h1, w1);
        cvt2(v[2*oc+1].x, v[2*oc+1].y, h2, w2);
        cvt2(v[2*oc+1].z, v[2*oc+1].w, h3, w3);
        *(uint4*)(dst + physlot(oc, o) * 16)     = make_uint4(h0, h1, h2, h3);
        *(uint4*)(dst + physlot(4 + oc, o) * 16) = make_uint4(w0, w1, w2, w3);
    }
}

// ---------------------------------------------------------------------------
// K1: MFMA GEMM, tile 512(o) x 128(n), BK=32, 512 threads = 8 waves (4x2 of
// 128x64). NEW: A fragments load DIRECTLY from L2-resident wcvt into VGPRs
// (no A-LDS, no DMA, no A barrier dependency); only the 16 KB B tile goes
// through LDS (double-buffered, 32 KB). One barrier per K-step guards B only.
// ---------------------------------------------------------------------------
template <bool PRE>
__global__ __launch_bounds__(512, 2) void gemm_mfma(
    const float* __restrict__ in,          // [B,512,3136]
    const float* __restrict__ wp,          // [1024,512] (fallback path)
    const unsigned char* __restrict__ wc,  // wcvt (fast path)
    const float* __restrict__ bp,          // [1024]
    float* __restrict__ gate,              // d_out
    float* __restrict__ scan)              // ws (+2MB on fast path)
{
    const int bx = blockIdx.x;   // 0..24 n-tiles of 128 (last is half)
    const int by = blockIdx.y;   // 0: gate, 1: scan
    const int b  = blockIdx.z;
    const int t  = threadIdx.x;
    const int lane = t & 63;
    const int wid  = t >> 6;           // 0..7
    const int wm = wid >> 1;           // o-strip of 128
    const int wn = wid & 1;            // n-strip of 64
    const int l15 = lane & 15, lko = lane >> 4;

    __shared__ __align__(16) unsigned char ldsB[32768];
    unsigned char* const B0 = ldsB;
    unsigned char* const B1 = ldsB + 16384;

    const int o0 = by * 512;
    const int n0 = bx * 128;

    // B staging role: thread (q = n-quad, kk = k-pair)
    const int q  = t & 31;
    const int kk = t >> 5;             // 0..15
    const int maxq = ((HW - n0) >> 2) - 1;
    const int qc = q < maxq ? q : maxq;
    const float* inB = in + (size_t)b * (CCH * (size_t)HW) + n0 + 4 * qc;

    const unsigned char* gAw = wc + (size_t)o0 * 2048;
    const int rbase0 = wm * 128 + l15;

    f32x4 acc[8][4] = {};
    float4 bc0, bc1;

    auto loadB = [&](int kt) {
        const float* p = inB + (size_t)(kt * 32 + 2 * kk) * HW;
        bc0 = *(const float4*)p;
        bc1 = *(const float4*)(p + HW);
    };

    auto writeB = [&](unsigned char* dB) {
        const int oc = kk >> 2, j4 = (kk & 3) * 4;
        unsigned hw_, lw_;
#define BCOL(C, COMP) \
        { const int nl = 4 * q + C; \
          unsigned char* row = dB + nl * 128; \
          cvt2(bc0.COMP, bc1.COMP, hw_, lw_); \
          *(unsigned*)(row + physlot(oc, nl) * 16 + j4)     = hw_; \
          *(unsigned*)(row + physlot(4 + oc, nl) * 16 + j4) = lw_; }
        BCOL(0, x) BCOL(1, y) BCOL(2, z) BCOL(3, w)
#undef BCOL
    };

    auto body = [&](int kt, unsigned char* Bc, unsigned char* Bn) {
        const bool notlast = (kt + 1 < NKT);

        // ---- write B(kt+1) into the other buffer (regs already loaded) ----
        if (notlast) writeB(Bn);

        // ---- A fragments: direct global loads (L2-resident wcvt) ----
        short8v ah[8], al[8];
        if constexpr (PRE) {
#pragma unroll
            for (int fi = 0; fi < 8; ++fi) {
                const int row = rbase0 + fi * 16;
                const unsigned char* pr = gAw + (size_t)row * 2048 + kt * 128;
                ah[fi] = *(const short8v*)(pr + physlot(lko, row) * 16);
                al[fi] = *(const short8v*)(pr + physlot(4 + lko, row) * 16);
            }
        } else {
#pragma unroll
            for (int fi = 0; fi < 8; ++fi) {
                const int row = rbase0 + fi * 16;
                const float* pa = wp + (size_t)(o0 + row) * CCH + kt * 32 + lko * 8;
                float4 a0 = *(const float4*)pa;
                float4 a1 = *(const float4*)(pa + 4);
                unsigned h0, l0, h1, l1, h2, l2, h3, l3;
                cvt2(a0.x, a0.y, h0, l0); cvt2(a0.z, a0.w, h1, l1);
                cvt2(a1.x, a1.y, h2, l2); cvt2(a1.z, a1.w, h3, l3);
                ah[fi] = pack4(h0, h1, h2, h3);
                al[fi] = pack4(l0, l1, l2, l3);
            }
        }

        // ---- refill B regs for kt+2 (stays in flight through the MFMAs) ----
        if (kt + 2 < NKT) loadB(kt + 2);

        // ---- B fragments from LDS ----
        short8v bfh[4], bfl[4];
#pragma unroll
        for (int g = 0; g < 4; ++g) {
            const int n = wn * 64 + g * 16 + l15;
            const unsigned char* rb = Bc + n * 128;
            bfh[g] = *(const short8v*)(rb + physlot(lko, n) * 16);
            bfl[g] = *(const short8v*)(rb + physlot(4 + lko, n) * 16);
        }

        // ---- MFMA stream (compiler inserts counted vmcnt for A regs) ----
        __builtin_amdgcn_s_setprio(1);
#pragma unroll
        for (int fi = 0; fi < 8; ++fi)
#pragma unroll
            for (int g = 0; g < 4; ++g) {
                f32x4 c = acc[fi][g];
                c = __builtin_amdgcn_mfma_f32_16x16x32_bf16(ah[fi], bfh[g], c, 0, 0, 0);
                c = __builtin_amdgcn_mfma_f32_16x16x32_bf16(al[fi], bfh[g], c, 0, 0, 0);
                c = __builtin_amdgcn_mfma_f32_16x16x32_bf16(ah[fi], bfl[g], c, 0, 0, 0);
                acc[fi][g] = c;
            }
        __builtin_amdgcn_s_setprio(0);

        // ---- barrier guards only the 16 KB B tile ----
        if (notlast) {
            asm volatile("s_waitcnt lgkmcnt(0)" ::: "memory");
            __builtin_amdgcn_s_barrier();
            asm volatile("" ::: "memory");
        }
    };

    // ---- prologue: B(0) -> LDS, B(1) -> regs ----
    loadB(0);
    writeB(B0);
    loadB(1);
    asm volatile("s_waitcnt lgkmcnt(0)" ::: "memory");
    __builtin_amdgcn_s_barrier();
    asm volatile("" ::: "memory");

#pragma unroll 1
    for (int kt2 = 0; kt2 < NKT; kt2 += 2) {
        body(kt2,     B0, B1);
        body(kt2 + 1, B1, B0);
    }

    // ---- epilogue: bias + store (C: row = lko*4+rg, col = l15) ----
    float* dstb = (by == 0) ? gate : scan;
#pragma unroll
    for (int f = 0; f < 8; ++f) {
        const int rowb = wm * 128 + f * 16 + lko * 4;
#pragma unroll
        for (int rg = 0; rg < 4; ++rg) {
            const int o = o0 + rowb + rg;
            const float bias = bp[o];
            float* drow = dstb + ((size_t)b * CCH + (o & (CCH - 1))) * HW;
#pragma unroll
            for (int g = 0; g < 4; ++g) {
                const int n = n0 + wn * 64 + g * 16 + l15;
                if (n < HW) drow[n] = acc[f][g][rg] + bias;
            }
        }
    }
}

// ---------------------------------------------------------------------------
// K2: per-(b,c) 2D discounted scan + fused epilogue (R0-proven).
// ---------------------------------------------------------------------------
__global__ __launch_bounds__(64) void scan_fuse(
    const float* __restrict__ in,
    const float* __restrict__ scanb,
    const float* __restrict__ disc,
    const float* __restrict__ gamma,
    float* gate_out)
{
    const int idx = blockIdx.x;
    const int c = idx & (CCH - 1);
    const size_t base = (size_t)idx * HW;
    const float d = disc[c];
    const float g = gamma[0];
    const int lane = threadIdx.x;

    __shared__ float L[WDIM * 57];

    if (lane < WDIM) {
        const int w = lane;
        float acc = 0.f;
#pragma unroll 4
        for (int h = 0; h < WDIM; h++) {
            acc = fmaf(d, acc, scanb[base + h * WDIM + w]);
            L[h * 57 + w] = acc;
        }
    }
    __syncthreads();
    if (lane < WDIM) {
        const int h = lane;
        float acc = 0.f;
#pragma unroll 4
        for (int w = 0; w < WDIM; w++) {
            acc = fmaf(d, acc, L[h * 57 + w]);
            L[h * 57 + w] = acc;
        }
    }
    __syncthreads();
    if (lane < WDIM) {
        const int w = lane;
#pragma unroll 4
        for (int h = 0; h < WDIM; h++) {
            const size_t off = base + h * WDIM + w;
            const float xc = L[h * 57 + w];
            const float sg = 1.f / (1.f + __expf(-xc));
            const float val = fmaf(g * gate_out[off], sg, in[off]);
            gate_out[off] = val;
        }
    }
}

extern "C" void kernel_launch(void* const* d_in, const int* in_sizes, int n_in,
                              void* d_out, int out_size, void* d_ws, size_t ws_size,
                              hipStream_t stream) {
    const float* in = (const float*)d_in[0];
    const float* wp = (const float*)d_in[1];
    const float* bp = (const float*)d_in[2];
    const float* dc = (const float*)d_in[3];
    const float* gm = (const float*)d_in[4];
    float* out = (float*)d_out;

    const size_t scan_bytes = (size_t)BATCH * CCH * HW * 4;   // 205.5 MB
    const size_t wcvt_bytes = (size_t)OCH * CCH * 4;          // 2 MB
    const bool pre = ws_size >= scan_bytes + wcvt_bytes;

    unsigned char* wcvt = (unsigned char*)d_ws;
    float* scanp = (float*)((unsigned char*)d_ws + (pre ? wcvt_bytes : 0));

    dim3 g1(25, 2, BATCH);
    if (pre) {
        preconv_w<<<64, 256, 0, stream>>>(wp, wcvt);
        gemm_mfma<true><<<g1, 512, 0, stream>>>(in, wp, wcvt, bp, out, scanp);
    } else {
        gemm_mfma<false><<<g1, 512, 0, stream>>>(in, wp, wcvt, bp, out, scanp);
    }

    scan_fuse<<<BATCH * CCH, 64, 0, stream>>>(in, scanp, dc, gm, out);
}

// Round 8
// 708.313 us; speedup vs baseline: 1.3029x; 1.3029x over previous
//
#include <hip/hip_runtime.h>
#include <cstddef>
#include <cstdint>

#define BATCH 32
#define CCH   512
#define OCH   1024
#define HW    3136
#define WDIM  56
#define NKT   16           // 512 / 32 logical-k per tile

typedef __attribute__((ext_vector_type(8))) short short8v;  // 8 bf16
typedef __attribute__((ext_vector_type(4))) float f32x4;

// pair of fp32 -> packed bf16 hi-word + lo-word (R1-proven numerics).
static __device__ __forceinline__ void cvt2(float x0, float x1,
                                            unsigned& hw, unsigned& lw) {
    unsigned u0 = __float_as_uint(x0), u1 = __float_as_uint(x1);
    hw = (u1 & 0xffff0000u) | (u0 >> 16);
    float l0 = x0 - __uint_as_float(u0 & 0xffff0000u);
    float l1 = x1 - __uint_as_float(u1 & 0xffff0000u);
    unsigned r0 = __float_as_uint(l0), r1 = __float_as_uint(l1);
    r0 = r0 + 0x7fffu + ((r0 >> 16) & 1u);
    r1 = r1 + 0x7fffu + ((r1 >> 16) & 1u);
    lw = (r1 & 0xffff0000u) | (r0 >> 16);
}

static __device__ __forceinline__ int physlot(int s, int row) {
    return (s ^ (row & 7) ^ ((row >> 3) & 7)) & 7;
}

#define GLD_LDS16(gsrc, ldst) \
    __builtin_amdgcn_global_load_lds( \
        (const __attribute__((address_space(1))) void*)(gsrc), \
        (__attribute__((address_space(3))) void*)(ldst), 16, 0, 0)

#define MFMA16(a, bb, c) __builtin_amdgcn_mfma_f32_16x16x32_bf16((a), (bb), (c), 0, 0, 0)

// ---------------------------------------------------------------------------
// K0: pre-convert weights into LDS-image layout (R3-proven):
// wcvt[o][kt] = 128 B: phys slots 0-3 <- hi k-octets, 4-7 <- lo k-octets,
// pre-swizzled with physlot(s, o) so the GEMM can gld_lds linear-copy.
// ---------------------------------------------------------------------------
__global__ __launch_bounds__(256) void preconv_w(
    const float* __restrict__ wp, unsigned char* __restrict__ wcvt)
{
    const int id = blockIdx.x * 256 + threadIdx.x;   // 16384 = 1024 o x 16 kt
    const int o = id >> 4, kt = id & 15;
    const float* p = wp + (size_t)o * CCH + kt * 32;
    unsigned char* dst = wcvt + (size_t)o * 2048 + kt * 128;
    float4 v[8];
#pragma unroll
    for (int r = 0; r < 8; ++r) v[r] = *(const float4*)(p + 4 * r);
#pragma unroll
    for (int oc = 0; oc < 4; ++oc) {
        unsigned h0, w0, h1, w1, h2, w2, h3, w3;
        cvt2(v[2*oc].x,   v[2*oc].y,   h0, w0);
        cvt2(v[2*oc].z,   v[2*oc].w,   h1, w1);
        cvt2(v[2*oc+1].x, v[2*oc+1].y, h2, w2);
        cvt2(v[2*oc+1].z, v[2*oc+1].w, h3, w3);
        *(uint4*)(dst + physlot(oc, o) * 16)     = make_uint4(h0, h1, h2, h3);
        *(uint4*)(dst + physlot(4 + oc, o) * 16) = make_uint4(w0, w1, w2, w3);
    }
}

// ---------------------------------------------------------------------------
// K1: 8-phase MFMA GEMM (m201-style schedule). Tile 256(o) x 256(n),
// 32 logical k per K-tile stored as 64 bf16 (hi|lo planes). 512 threads =
// 8 waves (2M x 4N), per-wave C = 128x64 (8x4 frags). LDS 128 KB: A/B each
// 2 dbuf x 256 rows x 128 B (physlot-swizzled rows).
// Per group (one K-tile computed, next staged): 4 phases, each
// {ds_read frags | stage piece | barrier | lgkmcnt(0) | 24 MFMA | barrier}.
// A staged by 4x gld_lds from pre-swizzled wcvt (1/phase); B reg-staged:
// fp32 loads issued phase 0 (T14), cvt+ds_write phase 3 after vmcnt(4);
// vmcnt(0) only at the group-tail barrier (tile handoff).
// ---------------------------------------------------------------------------
__global__ __launch_bounds__(512, 2) void gemm8p(
    const float* __restrict__ in,          // [B,512,3136]
    const unsigned char* __restrict__ wc,  // wcvt
    const float* __restrict__ bp,          // [1024]
    float* __restrict__ gate,              // d_out
    float* __restrict__ scan)              // ws + 2MB
{
    const int bx = blockIdx.x;   // 0..12 n-tiles of 256 (last is 64 valid)
    const int by = blockIdx.y;   // 0..3 o-tiles of 256
    const int b  = blockIdx.z;
    const int t  = threadIdx.x;
    const int lane = t & 63;
    const int wid  = t >> 6;           // 0..7
    const int wm = wid >> 2;           // o-strip of 128
    const int wn = wid & 3;            // n-strip of 64
    const int l15 = lane & 15, lko = lane >> 4;

    __shared__ __align__(16) unsigned char lds[131072];
    unsigned char* const A0 = lds;
    unsigned char* const A1 = lds + 32768;
    unsigned char* const B0 = lds + 65536;
    unsigned char* const B1 = lds + 98304;

    const int o0 = by * 256;
    const int n0 = bx * 256;

    // ---- B staging role: thread (q = n-quad 0..63, kg = k-quad 0..7) ----
    const int q  = t & 63;
    const int kg = t >> 6;
    const int maxq = ((HW - n0) >> 2) - 1;
    const int qc = q < maxq ? q : maxq;
    const float* inB = in + (size_t)b * (CCH * (size_t)HW) + n0 + 4 * qc;

    // ---- A staging: per-thread source base (row = t>>3, sub = t&7) ----
    const unsigned char* aSrc = wc + (size_t)(o0 + (t >> 3)) * 2048 + (t & 7) * 16;

    f32x4 acc[8][4] = {};
    float4 bc0, bc1, bc2, bc3;

    auto loadBg = [&](int kt) {
        const float* p = inB + (size_t)(kt * 32 + kg * 4) * HW;
        bc0 = *(const float4*)p;
        bc1 = *(const float4*)(p + HW);
        bc2 = *(const float4*)(p + 2 * (size_t)HW);
        bc3 = *(const float4*)(p + 3 * (size_t)HW);
    };

    auto writeB = [&](unsigned char* dB) {
        const int oc  = kg >> 1;
        const int wb8 = (kg & 1) * 8;
        unsigned h0, l0, h1, l1;
#define BCOL(C, COMP) \
        { const int nl = 4 * q + C; \
          unsigned char* row = dB + nl * 128; \
          cvt2(bc0.COMP, bc1.COMP, h0, l0); \
          cvt2(bc2.COMP, bc3.COMP, h1, l1); \
          *(uint2*)(row + physlot(oc, nl) * 16 + wb8)     = make_uint2(h0, h1); \
          *(uint2*)(row + physlot(4 + oc, nl) * 16 + wb8) = make_uint2(l0, l1); }
        BCOL(0, x) BCOL(1, y) BCOL(2, z) BCOL(3, w)
#undef BCOL
    };

    auto stA = [&](int kt, int r, unsigned char* An) {
        GLD_LDS16(aSrc + (size_t)(r * 64) * 2048 + kt * 128,
                  An + r * 8192 + wid * 1024);   // wave-uniform dest base
    };

    // one K-tile group: compute tile j from (Ac,Bc); stage tile j+1 into (An,Bn)
    auto group = [&](int j, unsigned char* Ac, unsigned char* Bc,
                     unsigned char* An, unsigned char* Bn, bool st) {
        short8v bfh[4], bfl[4];
#pragma unroll
        for (int p = 0; p < 4; ++p) {
            // ---- ds_read fragments for this phase ----
            if (p == 0) {
#pragma unroll
                for (int g = 0; g < 4; ++g) {
                    const int n = wn * 64 + g * 16 + l15;
                    const unsigned char* rb = Bc + n * 128;
                    bfh[g] = *(const short8v*)(rb + physlot(lko, n) * 16);
                    bfl[g] = *(const short8v*)(rb + physlot(4 + lko, n) * 16);
                }
            }
            const int r0 = wm * 128 + (p * 2) * 16 + l15;
            const int r1 = r0 + 16;
            const short8v ah0 = *(const short8v*)(Ac + r0 * 128 + physlot(lko, r0) * 16);
            const short8v al0 = *(const short8v*)(Ac + r0 * 128 + physlot(4 + lko, r0) * 16);
            const short8v ah1 = *(const short8v*)(Ac + r1 * 128 + physlot(lko, r1) * 16);
            const short8v al1 = *(const short8v*)(Ac + r1 * 128 + physlot(4 + lko, r1) * 16);

            // ---- staging piece for tile j+1 ----
            if (st) {
                if (p == 0)      { loadBg(j + 1); stA(j + 1, 0, An); }
                else if (p == 1) { stA(j + 1, 1, An); }
                else if (p == 2) { stA(j + 1, 2, An); stA(j + 1, 3, An); }
                else {
                    asm volatile("s_waitcnt vmcnt(4)" ::: "memory");  // B fp32 arrived
                    writeB(Bn);
                }
            }

            __builtin_amdgcn_s_barrier();
            asm volatile("s_waitcnt lgkmcnt(0)" ::: "memory");

            __builtin_amdgcn_s_setprio(1);
#pragma unroll
            for (int g = 0; g < 4; ++g) {
                f32x4 c = acc[p * 2][g];
                c = MFMA16(ah0, bfh[g], c);
                c = MFMA16(al0, bfh[g], c);
                c = MFMA16(ah0, bfl[g], c);
                acc[p * 2][g] = c;
                f32x4 d = acc[p * 2 + 1][g];
                d = MFMA16(ah1, bfh[g], d);
                d = MFMA16(al1, bfh[g], d);
                d = MFMA16(ah1, bfl[g], d);
                acc[p * 2 + 1][g] = d;
            }
            __builtin_amdgcn_s_setprio(0);

            if (p < 3) {
                __builtin_amdgcn_s_barrier();
            } else {
                if (st) asm volatile("s_waitcnt vmcnt(0)" ::: "memory"); // A DMA landed
                __builtin_amdgcn_s_barrier();   // tile handoff
            }
        }
    };

    // ---- prologue: stage tile 0 into buf0 ----
    loadBg(0);
    stA(0, 0, A0); stA(0, 1, A0); stA(0, 2, A0); stA(0, 3, A0);
    asm volatile("s_waitcnt vmcnt(4)" ::: "memory");
    writeB(B0);
    asm volatile("s_waitcnt vmcnt(0) lgkmcnt(0)" ::: "memory");
    __builtin_amdgcn_s_barrier();

#pragma unroll 1
    for (int j = 0; j < NKT; j += 2) {
        group(j,     A0, B0, A1, B1, true);
        group(j + 1, A1, B1, A0, B0, (j + 2) < NKT);
    }

    // ---- epilogue: bias + store (C: row = lko*4+rg, col = l15) ----
    float* dstb = (by < 2) ? gate : scan;
#pragma unroll
    for (int f = 0; f < 8; ++f) {
        const int rowb = wm * 128 + f * 16 + lko * 4;
#pragma unroll
        for (int rg = 0; rg < 4; ++rg) {
            const int o = o0 + rowb + rg;
            const float bias = bp[o];
            float* drow = dstb + ((size_t)b * CCH + (o & (CCH - 1))) * HW;
#pragma unroll
            for (int g = 0; g < 4; ++g) {
                const int n = n0 + wn * 64 + g * 16 + l15;
                if (n < HW) drow[n] = acc[f][g][rg] + bias;
            }
        }
    }
}

// ---------------------------------------------------------------------------
// Fallback GEMM (R0-proven fp32, only if ws too small for wcvt).
// ---------------------------------------------------------------------------
__global__ __launch_bounds__(256) void gemm_proj(
    const float* __restrict__ in, const float* __restrict__ wp,
    const float* __restrict__ bp, float* __restrict__ gate,
    float* __restrict__ scan)
{
    const int bx = blockIdx.x, by = blockIdx.y, b = blockIdx.z;
    const int t = threadIdx.x;
    __shared__ float As[16][128];
    __shared__ float Bs[16][64];
    const float* Ab = wp + (size_t)(by * 128) * CCH;
    const float* Bb = in + (size_t)b * CCH * HW + bx * 64;
    float acc[8][4];
#pragma unroll
    for (int i = 0; i < 8; i++)
#pragma unroll
        for (int j = 0; j < 4; j++) acc[i][j] = 0.f;
    const int a_row = t >> 1, a_c = (t & 1) * 8;
    const int b_row = t >> 4, b_n = (t & 15) * 4;
    const int ty = t >> 4, tx = t & 15;
    for (int k0 = 0; k0 < CCH; k0 += 16) {
        float4 av0 = *(const float4*)(Ab + (size_t)a_row * CCH + k0 + a_c);
        float4 av1 = *(const float4*)(Ab + (size_t)a_row * CCH + k0 + a_c + 4);
        float4 bv  = *(const float4*)(Bb + (size_t)(k0 + b_row) * HW + b_n);
        __syncthreads();
        As[a_c + 0][a_row] = av0.x; As[a_c + 1][a_row] = av0.y;
        As[a_c + 2][a_row] = av0.z; As[a_c + 3][a_row] = av0.w;
        As[a_c + 4][a_row] = av1.x; As[a_c + 5][a_row] = av1.y;
        As[a_c + 6][a_row] = av1.z; As[a_c + 7][a_row] = av1.w;
        *(float4*)&Bs[b_row][b_n] = bv;
        __syncthreads();
#pragma unroll
        for (int kk = 0; kk < 16; kk++) {
            float4 a0 = *(const float4*)&As[kk][ty * 8];
            float4 a1 = *(const float4*)&As[kk][ty * 8 + 4];
            float4 bb = *(const float4*)&Bs[kk][tx * 4];
            float av[8] = {a0.x, a0.y, a0.z, a0.w, a1.x, a1.y, a1.z, a1.w};
            float bw[4] = {bb.x, bb.y, bb.z, bb.w};
#pragma unroll
            for (int i = 0; i < 8; i++)
#pragma unroll
                for (int j = 0; j < 4; j++)
                    acc[i][j] = fmaf(av[i], bw[j], acc[i][j]);
        }
    }
    const int n0 = bx * 64 + tx * 4;
#pragma unroll
    for (int i = 0; i < 8; i++) {
        const int o = by * 128 + ty * 8 + i;
        const float bias = bp[o];
        float4 v;
        v.x = acc[i][0] + bias; v.y = acc[i][1] + bias;
        v.z = acc[i][2] + bias; v.w = acc[i][3] + bias;
        float* dst;
        if (o < CCH) dst = gate + ((size_t)b * CCH + o) * HW + n0;
        else         dst = scan + ((size_t)b * CCH + (o - CCH)) * HW + n0;
        *(float4*)dst = v;
    }
}

// ---------------------------------------------------------------------------
// K2: per-(b,c) 2D discounted scan + fused epilogue (R0-proven).
// ---------------------------------------------------------------------------
__global__ __launch_bounds__(64) void scan_fuse(
    const float* __restrict__ in,
    const float* __restrict__ scanb,
    const float* __restrict__ disc,
    const float* __restrict__ gamma,
    float* gate_out)
{
    const int idx = blockIdx.x;
    const int c = idx & (CCH - 1);
    const size_t base = (size_t)idx * HW;
    const float d = disc[c];
    const float g = gamma[0];
    const int lane = threadIdx.x;

    __shared__ float L[WDIM * 57];

    if (lane < WDIM) {
        const int w = lane;
        float acc = 0.f;
#pragma unroll 4
        for (int h = 0; h < WDIM; h++) {
            acc = fmaf(d, acc, scanb[base + h * WDIM + w]);
            L[h * 57 + w] = acc;
        }
    }
    __syncthreads();
    if (lane < WDIM) {
        const int h = lane;
        float acc = 0.f;
#pragma unroll 4
        for (int w = 0; w < WDIM; w++) {
            acc = fmaf(d, acc, L[h * 57 + w]);
            L[h * 57 + w] = acc;
        }
    }
    __syncthreads();
    if (lane < WDIM) {
        const int w = lane;
#pragma unroll 4
        for (int h = 0; h < WDIM; h++) {
            const size_t off = base + h * WDIM + w;
            const float xc = L[h * 57 + w];
            const float sg = 1.f / (1.f + __expf(-xc));
            const float val = fmaf(g * gate_out[off], sg, in[off]);
            gate_out[off] = val;
        }
    }
}

extern "C" void kernel_launch(void* const* d_in, const int* in_sizes, int n_in,
                              void* d_out, int out_size, void* d_ws, size_t ws_size,
                              hipStream_t stream) {
    const float* in = (const float*)d_in[0];
    const float* wp = (const float*)d_in[1];
    const float* bp = (const float*)d_in[2];
    const float* dc = (const float*)d_in[3];
    const float* gm = (const float*)d_in[4];
    float* out = (float*)d_out;

    const size_t scan_bytes = (size_t)BATCH * CCH * HW * 4;   // 205.5 MB
    const size_t wcvt_bytes = (size_t)OCH * CCH * 4;          // 2 MB
    const bool pre = ws_size >= scan_bytes + wcvt_bytes;

    unsigned char* wcvt = (unsigned char*)d_ws;
    float* scanp = (float*)((unsigned char*)d_ws + (pre ? wcvt_bytes : 0));

    if (pre) {
        preconv_w<<<64, 256, 0, stream>>>(wp, wcvt);
        gemm8p<<<dim3(13, 4, BATCH), 512, 0, stream>>>(in, wcvt, bp, out, scanp);
    } else {
        gemm_proj<<<dim3(HW / 64, OCH / 128, BATCH), 256, 0, stream>>>(
            in, wp, bp, out, scanp);
    }

    scan_fuse<<<BATCH * CCH, 64, 0, stream>>>(in, scanp, dc, gm, out);
}